// Round 8
// baseline (255.993 us; speedup 1.0000x reference)
//
#include <hip/hip_runtime.h>
#include <cstddef>
#include <cstdint>

#define BB 4
#define TT 2048
#define CC 1024
#define LL 256
#define HH 16
#define DD 64   // head size
#define QLD (CC + LL)  // 1280: row stride of fused q|latent buffer

typedef __attribute__((ext_vector_type(8))) short s16x8;
typedef __attribute__((ext_vector_type(4))) float f32x4;

static __device__ inline unsigned short f2bf(float f) {
    union { float f; unsigned u; } v; v.f = f;
    unsigned r = v.u + 0x7fffu + ((v.u >> 16) & 1u);  // RNE
    return (unsigned short)(r >> 16);
}

static __device__ inline float fast_exp2(float x) {
#if __has_builtin(__builtin_amdgcn_exp2f)
    return __builtin_amdgcn_exp2f(x);
#else
    return exp2f(x);
#endif
}

// pack two f32 -> two bf16 (truncation) in one v_perm_b32
static __device__ inline unsigned pack_bf16_trunc(float lo, float hi) {
    union { float f; unsigned u; } a, b;
    a.f = lo; b.f = hi;
    return __builtin_amdgcn_perm(b.u, a.u, 0x07060302u);
}

// async global->LDS, 16B per lane; LDS dest = wave-uniform base + lane*16
#define GLDS16(g, l)                                             \
    __builtin_amdgcn_global_load_lds(                            \
        (__attribute__((address_space(1))) void*)(g),            \
        (__attribute__((address_space(3))) void*)(l), 16, 0, 0)

// ====================== fused conversion kernel =============================
// blocks [0, 8192): x fp32 -> bf16 (1024 elems/block)
// blocks [8192, 8896): one 64x64 transpose tile of a weight matrix
extern "C" __global__ __launch_bounds__(256)
void fused_cvt(const float* __restrict__ x, unsigned short* __restrict__ xb,
               const float* __restrict__ Wq, const float* __restrict__ Wkv,
               const float* __restrict__ Wk, const float* __restrict__ Wv,
               const float* __restrict__ Wo,
               unsigned short* __restrict__ W1t, unsigned short* __restrict__ W2t,
               unsigned short* __restrict__ Wot, float qscale) {
    __shared__ unsigned short Ts[64][72];
    const int t = threadIdx.x;
    int blk = blockIdx.x;
    if (blk < 8192) {
        const int i = blk * 256 + t;
        const float4 v = ((const float4*)x)[i];
        ushort4 o;
        o.x = f2bf(v.x); o.y = f2bf(v.y); o.z = f2bf(v.z); o.w = f2bf(v.w);
        ((ushort4*)xb)[i] = o;
        return;
    }
    blk -= 8192;
    const float* W; unsigned short* Wt; int K, N; float scale; int tile;
    if (blk < 256)      { W = Wq;  Wt = W1t;                      K = CC; N = CC; scale = qscale; tile = blk; }
    else if (blk < 320) { W = Wkv; Wt = W1t + (size_t)CC * CC;    K = CC; N = LL; scale = 1.f;    tile = blk - 256; }
    else if (blk < 384) { W = Wk;  Wt = W2t;                      K = LL; N = CC; scale = 1.f;    tile = blk - 320; }
    else if (blk < 448) { W = Wv;  Wt = W2t + (size_t)CC * LL;    K = LL; N = CC; scale = 1.f;    tile = blk - 384; }
    else                { W = Wo;  Wt = Wot;                      K = CC; N = CC; scale = 1.f;    tile = blk - 448; }
    const int ktiles = K >> 6;
    const int k0 = (tile % ktiles) * 64, n0 = (tile / ktiles) * 64;
#pragma unroll
    for (int l = 0; l < 4; ++l) {
        const int idx = t + l * 256;
        const int r = idx >> 4, c4 = (idx & 15) * 4;
        const float4 v = *(const float4*)(W + (size_t)(k0 + r) * N + n0 + c4);
        Ts[c4 + 0][r] = f2bf(v.x * scale); Ts[c4 + 1][r] = f2bf(v.y * scale);
        Ts[c4 + 2][r] = f2bf(v.z * scale); Ts[c4 + 3][r] = f2bf(v.w * scale);
    }
    __syncthreads();
#pragma unroll
    for (int l = 0; l < 2; ++l) {
        const int idx = t + l * 256;
        const int n = idx >> 3, seg = idx & 7;
        *(s16x8*)(Wt + (size_t)(n0 + n) * K + k0 + seg * 8) = *(const s16x8*)&Ts[n][seg * 8];
    }
}

// ========== bf16 MFMA GEMM: C[M,N] = A[M,K] @ Bt[N,K]^T ====================
// 128x128 tile, BK=64, 256 threads = 4 waves (2x2), 4x4 16x16x32 MFMA per wave.
// Staging via global_load_lds with XOR source swizzle (2-way banked reads).
// MODE 0: fp32 store (ldc) | MODE 1: bf16 store (ldc)
// MODE 3: cols < CC -> bf16 store (ldc); cols >= CC -> transposed vt store
template <int MODE>
__global__ __launch_bounds__(256)
void bgemm(const unsigned short* __restrict__ A, const unsigned short* __restrict__ Bt,
           void* __restrict__ Cv, void* __restrict__ Cv2,
           int M, int N, int K, int lda, int ldc) {
    __shared__ unsigned short As[128][64];
    __shared__ unsigned short Bs[128][64];
    const int t = threadIdx.x;
    const int w = t >> 6, lane = t & 63, quad = lane >> 4, l16 = lane & 15;
    const int wm = w & 1, wn = w >> 1;
    const int row0 = blockIdx.y * 128, col0 = blockIdx.x * 128;
    const int sr = lane >> 3;                 // row within an 8-row chunk
    const int sc = ((lane & 7) ^ sr) * 8;     // swizzled 16B source segment

    f32x4 acc[4][4];
#pragma unroll
    for (int i = 0; i < 4; ++i)
#pragma unroll
        for (int j = 0; j < 4; ++j) acc[i][j] = (f32x4){0.f, 0.f, 0.f, 0.f};

    const unsigned short* Ab = A + (size_t)(row0 + w * 32 + sr) * lda + sc;
    const unsigned short* Bb = Bt + (size_t)(col0 + w * 32 + sr) * K + sc;

    for (int k0 = 0; k0 < K; k0 += 64) {
#pragma unroll
        for (int c = 0; c < 4; ++c) {
            GLDS16(Ab + (size_t)(c * 8) * lda + k0, &As[w * 32 + c * 8][0]);
            GLDS16(Bb + (size_t)(c * 8) * K + k0, &Bs[w * 32 + c * 8][0]);
        }
        __syncthreads();
#pragma unroll
        for (int kk = 0; kk < 2; ++kk) {
            s16x8 af[4], bfr[4];
#pragma unroll
            for (int mt = 0; mt < 4; ++mt)
                af[mt] = *(const s16x8*)
                    &As[wm * 64 + mt * 16 + l16][((kk * 4 + quad) ^ (l16 & 7)) * 8];
#pragma unroll
            for (int nt = 0; nt < 4; ++nt)
                bfr[nt] = *(const s16x8*)
                    &Bs[wn * 64 + nt * 16 + l16][((kk * 4 + quad) ^ (l16 & 7)) * 8];
#pragma unroll
            for (int mt = 0; mt < 4; ++mt)
#pragma unroll
                for (int nt = 0; nt < 4; ++nt)
                    acc[mt][nt] = __builtin_amdgcn_mfma_f32_16x16x32_bf16(
                        af[mt], bfr[nt], acc[mt][nt], 0, 0, 0);
        }
        __syncthreads();
    }

    if constexpr (MODE == 0) {
        float* C = (float*)Cv;
#pragma unroll
        for (int mt = 0; mt < 4; ++mt)
#pragma unroll
            for (int nt = 0; nt < 4; ++nt)
#pragma unroll
                for (int r = 0; r < 4; ++r)
                    C[(size_t)(row0 + wm * 64 + mt * 16 + quad * 4 + r) * ldc +
                      col0 + wn * 64 + nt * 16 + l16] = acc[mt][nt][r];
    } else if constexpr (MODE == 1) {
        unsigned short* C = (unsigned short*)Cv;
#pragma unroll
        for (int mt = 0; mt < 4; ++mt)
#pragma unroll
            for (int nt = 0; nt < 4; ++nt)
#pragma unroll
                for (int r = 0; r < 4; ++r)
                    C[(size_t)(row0 + wm * 64 + mt * 16 + quad * 4 + r) * ldc +
                      col0 + wn * 64 + nt * 16 + l16] = f2bf(acc[mt][nt][r]);
    } else {
        if (col0 < CC) {
            unsigned short* C = (unsigned short*)Cv;
#pragma unroll
            for (int mt = 0; mt < 4; ++mt)
#pragma unroll
                for (int nt = 0; nt < 4; ++nt)
#pragma unroll
                    for (int r = 0; r < 4; ++r)
                        C[(size_t)(row0 + wm * 64 + mt * 16 + quad * 4 + r) * ldc +
                          col0 + wn * 64 + nt * 16 + l16] = f2bf(acc[mt][nt][r]);
        } else {
            // v-half: transposed store vt[b][h][dv][t]
            __shared__ unsigned short Tb[64][136];
            unsigned short* vt = (unsigned short*)Cv2;
            const int b   = row0 >> 11;  // 2048 tokens per batch; tile never crosses
            const int tl0 = row0 & 2047;
#pragma unroll
            for (int h = 0; h < 2; ++h) {
                if (wn == h) {
#pragma unroll
                    for (int mt = 0; mt < 4; ++mt)
#pragma unroll
                        for (int nt = 0; nt < 4; ++nt)
#pragma unroll
                            for (int r = 0; r < 4; ++r)
                                Tb[nt * 16 + l16][wm * 64 + mt * 16 + quad * 4 + r] =
                                    f2bf(acc[mt][nt][r]);
                }
                __syncthreads();
                const int head = ((col0 - CC) >> 6) + h;
#pragma unroll
                for (int l = 0; l < 4; ++l) {
                    const int idx = t + l * 256;
                    const int dv = idx >> 4, seg = idx & 15;
                    *(s16x8*)(vt + (((size_t)b * HH + head) * DD + dv) * TT + tl0 + seg * 8) =
                        *(const s16x8*)&Tb[dv][seg * 8];
                }
                __syncthreads();
            }
        }
    }
}

// ============ Flash attention v3: paired q-tiles, shared staging ============
// grid (B*H, 8); block 512 threads = 8 waves.
// Block j handles q-tiles qt2A = 15-j (waves 0-3) and qt2B = j (waves 4-7).
// B's causal key range is a subset of A's, so K/V tiles are staged ONCE per kt
// and shared; B-waves self-idle via the wave-uniform guard once past their
// range. Heavy blocks (j=0) dispatch first. All 512 blocks co-resident
// (LDS 52 KB -> 2 blocks/CU, 16 waves/CU held for the whole dispatch).
// q: bf16 [b][t][QLD] (q|latent fused, pre-scaled by 0.125*log2(e));
// k: bf16 [b][t][h*64+d]; vt: bf16 [b][h][dv][t]; y: bf16 [b][t][c].
extern "C" __global__ __launch_bounds__(512)
void mla_attn3(const unsigned short* __restrict__ q,
               const unsigned short* __restrict__ k,
               const unsigned short* __restrict__ vt,
               unsigned short* __restrict__ y) {
    __shared__ unsigned short Ks[64][64];     // [key][d], source-XOR-swizzled segs
    __shared__ unsigned short Vs[64][64];     // [dv][key], source-XOR-swizzled segs
    __shared__ unsigned short Ps[8][32][72];  // per-wave [qloc][key], padded

    const int bh = blockIdx.x;
    const int j  = blockIdx.y;                 // 0 = heaviest pair, dispatched first
    const int b = bh >> 4, h = bh & 15;
    const int t = threadIdx.x;
    const int w = t >> 6, lane = t & 63, quad = lane >> 4, l16 = lane & 15;
    const int grp = w >> 2;                    // 0 = tile A (15-j), 1 = tile B (j)
    const int wl  = w & 3;
    const int t0  = (grp ? j : (15 - j)) * 128;
    const int qw0 = t0 + wl * 32;              // wave's first query
    const int swz = ((lane & 7) ^ ((lane >> 3) & 7)) * 8;  // swizzled source seg
    const int lrow = lane >> 3;                // row within 8-row chunk

    const unsigned short* kb0 = k + ((size_t)b * TT) * CC + h * DD;
    const unsigned short* vb0 = vt + ((size_t)(b * HH + h)) * DD * TT;

    // Q fragments straight from global (pre-scaled), hoisted
    s16x8 qf[2][2];
#pragma unroll
    for (int qs = 0; qs < 2; ++qs)
#pragma unroll
        for (int kh = 0; kh < 2; ++kh)
            qf[qs][kh] = *(const s16x8*)(q + ((size_t)b * TT + qw0 + qs * 16 + l16) * QLD +
                                         h * DD + kh * 32 + quad * 8);

    f32x4 o[2][4];
    float lsum[2] = {0.f, 0.f};
#pragma unroll
    for (int qs = 0; qs < 2; ++qs)
#pragma unroll
        for (int nt = 0; nt < 4; ++nt) o[qs][nt] = (f32x4){0.f, 0.f, 0.f, 0.f};

    const int nkt = 2 * (15 - j) + 2;          // A's range covers B's
    for (int kt = 0; kt < nkt; ++kt) {
        const int s0 = kt * 64;
        // stage K,V tiles: 8 chunks each of 8 rows; wave w covers chunk w
        {
            const int row = w * 8 + lrow;
            GLDS16(kb0 + (size_t)(s0 + row) * CC + swz, &Ks[w * 8][0]);
            GLDS16(vb0 + (size_t)row * TT + s0 + swz, &Vs[w * 8][0]);
        }
        __syncthreads();

        if (s0 <= qw0 + 31) {  // wave-uniform: any unmasked element for this wave?
            // S^T = K Q^T : A=K[m=key], B=Q^T[k=d][n=q]; D row=key, col=q
            f32x4 st[2][4];
#pragma unroll
            for (int nt = 0; nt < 4; ++nt) {
                const int key = nt * 16 + l16;
                const s16x8 kf0 = *(const s16x8*)&Ks[key][((0 + quad) ^ (l16 & 7)) * 8];
                const s16x8 kf1 = *(const s16x8*)&Ks[key][((4 + quad) ^ (l16 & 7)) * 8];
#pragma unroll
                for (int qs = 0; qs < 2; ++qs) {
                    f32x4 acc = (f32x4){0.f, 0.f, 0.f, 0.f};
                    acc = __builtin_amdgcn_mfma_f32_16x16x32_bf16(kf0, qf[qs][0], acc, 0, 0, 0);
                    acc = __builtin_amdgcn_mfma_f32_16x16x32_bf16(kf1, qf[qs][1], acc, 0, 0, 0);
                    st[qs][nt] = acc;
                }
            }

            const bool maskedTile = (s0 + 63 > qw0);  // wave-uniform
#pragma unroll
            for (int qs = 0; qs < 2; ++qs) {
                const int qidx = qw0 + qs * 16 + l16;
#pragma unroll
                for (int nt = 0; nt < 4; ++nt) {
                    const int key0 = s0 + nt * 16 + quad * 4;
                    float p[4];
#pragma unroll
                    for (int r = 0; r < 4; ++r) {
                        float sv = st[qs][nt][r];
                        if (maskedTile && (key0 + r > qidx)) sv = -1e30f;
                        const float e = fast_exp2(sv);
                        p[r] = e;
                        lsum[qs] += e;
                    }
                    const unsigned lo = pack_bf16_trunc(p[0], p[1]);
                    const unsigned hi = pack_bf16_trunc(p[2], p[3]);
                    uint2 pk; pk.x = lo; pk.y = hi;
                    *(uint2*)&Ps[w][qs * 16 + l16][nt * 16 + quad * 4] = pk;
                }
            }

            // PV: A=P[m=q][k=key] from Ps rows; B=V[k=key][n=dv] from Vs rows
            s16x8 pf[2][2];
#pragma unroll
            for (int qs = 0; qs < 2; ++qs)
#pragma unroll
                for (int kh = 0; kh < 2; ++kh)
                    pf[qs][kh] = *(const s16x8*)&Ps[w][qs * 16 + l16][kh * 32 + quad * 8];
#pragma unroll
            for (int nt = 0; nt < 4; ++nt) {
                const int dv = nt * 16 + l16;
                const s16x8 vf0 = *(const s16x8*)&Vs[dv][((0 + quad) ^ (l16 & 7)) * 8];
                const s16x8 vf1 = *(const s16x8*)&Vs[dv][((4 + quad) ^ (l16 & 7)) * 8];
#pragma unroll
                for (int qs = 0; qs < 2; ++qs) {
                    o[qs][nt] = __builtin_amdgcn_mfma_f32_16x16x32_bf16(pf[qs][0], vf0,
                                                                        o[qs][nt], 0, 0, 0);
                    o[qs][nt] = __builtin_amdgcn_mfma_f32_16x16x32_bf16(pf[qs][1], vf1,
                                                                        o[qs][nt], 0, 0, 0);
                }
            }
        }
        __syncthreads();
    }

    // final l reduction: quads hold partial sums for query qs*16+l16
    float lfull[2];
#pragma unroll
    for (int qs = 0; qs < 2; ++qs) {
        float s = lsum[qs];
        s += __shfl_xor(s, 16);
        s += __shfl_xor(s, 32);
        lfull[qs] = s;
    }

    // store: o element = (query qs*16+quad*4+r, dv nt*16+l16)
#pragma unroll
    for (int qs = 0; qs < 2; ++qs) {
#pragma unroll
        for (int r = 0; r < 4; ++r) {
            const float inv = 1.f / __shfl(lfull[qs], quad * 4 + r);
            unsigned short* yb = y + ((size_t)b * TT + qw0 + qs * 16 + quad * 4 + r) * CC +
                                 h * DD + l16;
#pragma unroll
            for (int nt = 0; nt < 4; ++nt)
                yb[nt * 16] = f2bf(o[qs][nt][r] * inv);
        }
    }
}

extern "C" void kernel_launch(void* const* d_in, const int* in_sizes, int n_in,
                              void* d_out, int out_size, void* d_ws, size_t ws_size,
                              hipStream_t stream) {
    const float* x   = (const float*)d_in[0];
    const float* Wq  = (const float*)d_in[1];
    const float* Wkv = (const float*)d_in[2];
    const float* Wk  = (const float*)d_in[3];
    const float* Wv  = (const float*)d_in[4];
    const float* Wo  = (const float*)d_in[5];
    float* out = (float*)d_out;

    const int M = BB * TT;  // 8192
    unsigned short* p = (unsigned short*)d_ws;
    unsigned short* xb    = p; p += (size_t)M * CC;     // bf16 x
    unsigned short* qlatb = p; p += (size_t)M * QLD;    // fused q | latent
    unsigned short* kb    = p; p += (size_t)M * CC;
    unsigned short* vtb   = p; p += (size_t)M * CC;
    unsigned short* yb    = p; p += (size_t)M * CC;
    unsigned short* W1t   = p; p += (size_t)QLD * CC;   // [Wq^T ; Wkv^T]  [1280][1024]
    unsigned short* W2t   = p; p += (size_t)(2 * CC) * LL;  // [Wk^T ; Wv^T] [2048][256]
    unsigned short* Wot   = p; p += (size_t)CC * CC;

    const float qscale = 0.125f * 1.44269504f;  // 1/sqrt(64) * log2(e), folded into Wq

    fused_cvt<<<8896, 256, 0, stream>>>(x, xb, Wq, Wkv, Wk, Wv, Wo,
                                        W1t, W2t, Wot, qscale);
    // fused q|latent projection: [M,1280] = x @ [Wq | Wkv]
    bgemm<1><<<dim3(QLD / 128, M / 128), 256, 0, stream>>>(
        xb, W1t, qlatb, nullptr, M, QLD, CC, CC, QLD);
    // fused k|v up-projection: k half -> kb, v half -> vtb (transposed)
    bgemm<3><<<dim3(2 * CC / 128, M / 128), 256, 0, stream>>>(
        qlatb + CC, W2t, kb, vtb, M, 2 * CC, LL, QLD, CC);
    mla_attn3<<<dim3(BB * HH, 8), 512, 0, stream>>>(qlatb, kb, vtb, yb);
    bgemm<0><<<dim3(CC / 128, M / 128), 256, 0, stream>>>(
        yb, Wot, out, nullptr, M, CC, CC, CC, CC);
}

// Round 9
// 234.959 us; speedup vs baseline: 1.0895x; 1.0895x over previous
//
#include <hip/hip_runtime.h>
#include <cstddef>
#include <cstdint>

#define BB 4
#define TT 2048
#define CC 1024
#define LL 256
#define HH 16
#define DD 64   // head size
#define QLD (CC + LL)  // 1280: row stride of fused q|latent buffer

typedef __attribute__((ext_vector_type(8))) short s16x8;
typedef __attribute__((ext_vector_type(4))) float f32x4;

static __device__ inline unsigned short f2bf(float f) {
    union { float f; unsigned u; } v; v.f = f;
    unsigned r = v.u + 0x7fffu + ((v.u >> 16) & 1u);  // RNE
    return (unsigned short)(r >> 16);
}

static __device__ inline float fast_exp2(float x) {
#if __has_builtin(__builtin_amdgcn_exp2f)
    return __builtin_amdgcn_exp2f(x);
#else
    return exp2f(x);
#endif
}

// pack two f32 -> two bf16 (truncation) in one v_perm_b32
static __device__ inline unsigned pack_bf16_trunc(float lo, float hi) {
    union { float f; unsigned u; } a, b;
    a.f = lo; b.f = hi;
    return __builtin_amdgcn_perm(b.u, a.u, 0x07060302u);
}

// async global->LDS, 16B per lane; LDS dest = wave-uniform base + lane*16
#define GLDS16(g, l)                                             \
    __builtin_amdgcn_global_load_lds(                            \
        (__attribute__((address_space(1))) void*)(g),            \
        (__attribute__((address_space(3))) void*)(l), 16, 0, 0)

// ====================== fused conversion kernel =============================
// blocks [0, 8192): x fp32 -> bf16 (1024 elems/block)
// blocks [8192, 8896): one 64x64 transpose tile of a weight matrix
extern "C" __global__ __launch_bounds__(256)
void fused_cvt(const float* __restrict__ x, unsigned short* __restrict__ xb,
               const float* __restrict__ Wq, const float* __restrict__ Wkv,
               const float* __restrict__ Wk, const float* __restrict__ Wv,
               const float* __restrict__ Wo,
               unsigned short* __restrict__ W1t, unsigned short* __restrict__ W2t,
               unsigned short* __restrict__ Wot, float qscale) {
    __shared__ unsigned short Ts[64][72];
    const int t = threadIdx.x;
    int blk = blockIdx.x;
    if (blk < 8192) {
        const int i = blk * 256 + t;
        const float4 v = ((const float4*)x)[i];
        ushort4 o;
        o.x = f2bf(v.x); o.y = f2bf(v.y); o.z = f2bf(v.z); o.w = f2bf(v.w);
        ((ushort4*)xb)[i] = o;
        return;
    }
    blk -= 8192;
    const float* W; unsigned short* Wt; int K, N; float scale; int tile;
    if (blk < 256)      { W = Wq;  Wt = W1t;                      K = CC; N = CC; scale = qscale; tile = blk; }
    else if (blk < 320) { W = Wkv; Wt = W1t + (size_t)CC * CC;    K = CC; N = LL; scale = 1.f;    tile = blk - 256; }
    else if (blk < 384) { W = Wk;  Wt = W2t;                      K = LL; N = CC; scale = 1.f;    tile = blk - 320; }
    else if (blk < 448) { W = Wv;  Wt = W2t + (size_t)CC * LL;    K = LL; N = CC; scale = 1.f;    tile = blk - 384; }
    else                { W = Wo;  Wt = Wot;                      K = CC; N = CC; scale = 1.f;    tile = blk - 448; }
    const int ktiles = K >> 6;
    const int k0 = (tile % ktiles) * 64, n0 = (tile / ktiles) * 64;
#pragma unroll
    for (int l = 0; l < 4; ++l) {
        const int idx = t + l * 256;
        const int r = idx >> 4, c4 = (idx & 15) * 4;
        const float4 v = *(const float4*)(W + (size_t)(k0 + r) * N + n0 + c4);
        Ts[c4 + 0][r] = f2bf(v.x * scale); Ts[c4 + 1][r] = f2bf(v.y * scale);
        Ts[c4 + 2][r] = f2bf(v.z * scale); Ts[c4 + 3][r] = f2bf(v.w * scale);
    }
    __syncthreads();
#pragma unroll
    for (int l = 0; l < 2; ++l) {
        const int idx = t + l * 256;
        const int n = idx >> 3, seg = idx & 7;
        *(s16x8*)(Wt + (size_t)(n0 + n) * K + k0 + seg * 8) = *(const s16x8*)&Ts[n][seg * 8];
    }
}

// ========== bf16 MFMA GEMM: C[M,N] = A[M,K] @ Bt[N,K]^T ====================
// 128x128 tile, BK=64, 256 threads = 4 waves (2x2), 4x4 16x16x32 MFMA per wave.
// Staging via global_load_lds with XOR source swizzle (2-way banked reads).
// MODE 0: fp32 store (ldc) | MODE 1: bf16 store (ldc)
// MODE 3: cols < CC -> bf16 store (ldc); cols >= CC -> transposed vt store
template <int MODE>
__global__ __launch_bounds__(256)
void bgemm(const unsigned short* __restrict__ A, const unsigned short* __restrict__ Bt,
           void* __restrict__ Cv, void* __restrict__ Cv2,
           int M, int N, int K, int lda, int ldc) {
    __shared__ unsigned short As[128][64];
    __shared__ unsigned short Bs[128][64];
    const int t = threadIdx.x;
    const int w = t >> 6, lane = t & 63, quad = lane >> 4, l16 = lane & 15;
    const int wm = w & 1, wn = w >> 1;
    const int row0 = blockIdx.y * 128, col0 = blockIdx.x * 128;
    const int sr = lane >> 3;                 // row within an 8-row chunk
    const int sc = ((lane & 7) ^ sr) * 8;     // swizzled 16B source segment

    f32x4 acc[4][4];
#pragma unroll
    for (int i = 0; i < 4; ++i)
#pragma unroll
        for (int j = 0; j < 4; ++j) acc[i][j] = (f32x4){0.f, 0.f, 0.f, 0.f};

    const unsigned short* Ab = A + (size_t)(row0 + w * 32 + sr) * lda + sc;
    const unsigned short* Bb = Bt + (size_t)(col0 + w * 32 + sr) * K + sc;

    for (int k0 = 0; k0 < K; k0 += 64) {
#pragma unroll
        for (int c = 0; c < 4; ++c) {
            GLDS16(Ab + (size_t)(c * 8) * lda + k0, &As[w * 32 + c * 8][0]);
            GLDS16(Bb + (size_t)(c * 8) * K + k0, &Bs[w * 32 + c * 8][0]);
        }
        __syncthreads();
#pragma unroll
        for (int kk = 0; kk < 2; ++kk) {
            s16x8 af[4], bfr[4];
#pragma unroll
            for (int mt = 0; mt < 4; ++mt)
                af[mt] = *(const s16x8*)
                    &As[wm * 64 + mt * 16 + l16][((kk * 4 + quad) ^ (l16 & 7)) * 8];
#pragma unroll
            for (int nt = 0; nt < 4; ++nt)
                bfr[nt] = *(const s16x8*)
                    &Bs[wn * 64 + nt * 16 + l16][((kk * 4 + quad) ^ (l16 & 7)) * 8];
#pragma unroll
            for (int mt = 0; mt < 4; ++mt)
#pragma unroll
                for (int nt = 0; nt < 4; ++nt)
                    acc[mt][nt] = __builtin_amdgcn_mfma_f32_16x16x32_bf16(
                        af[mt], bfr[nt], acc[mt][nt], 0, 0, 0);
        }
        __syncthreads();
    }

    if constexpr (MODE == 0) {
        float* C = (float*)Cv;
#pragma unroll
        for (int mt = 0; mt < 4; ++mt)
#pragma unroll
            for (int nt = 0; nt < 4; ++nt)
#pragma unroll
                for (int r = 0; r < 4; ++r)
                    C[(size_t)(row0 + wm * 64 + mt * 16 + quad * 4 + r) * ldc +
                      col0 + wn * 64 + nt * 16 + l16] = acc[mt][nt][r];
    } else if constexpr (MODE == 1) {
        unsigned short* C = (unsigned short*)Cv;
#pragma unroll
        for (int mt = 0; mt < 4; ++mt)
#pragma unroll
            for (int nt = 0; nt < 4; ++nt)
#pragma unroll
                for (int r = 0; r < 4; ++r)
                    C[(size_t)(row0 + wm * 64 + mt * 16 + quad * 4 + r) * ldc +
                      col0 + wn * 64 + nt * 16 + l16] = f2bf(acc[mt][nt][r]);
    } else {
        if (col0 < CC) {
            unsigned short* C = (unsigned short*)Cv;
#pragma unroll
            for (int mt = 0; mt < 4; ++mt)
#pragma unroll
                for (int nt = 0; nt < 4; ++nt)
#pragma unroll
                    for (int r = 0; r < 4; ++r)
                        C[(size_t)(row0 + wm * 64 + mt * 16 + quad * 4 + r) * ldc +
                          col0 + wn * 64 + nt * 16 + l16] = f2bf(acc[mt][nt][r]);
        } else {
            // v-half: transposed store vt[b][h][dv][t]
            __shared__ unsigned short Tb[64][136];
            unsigned short* vt = (unsigned short*)Cv2;
            const int b   = row0 >> 11;  // 2048 tokens per batch; tile never crosses
            const int tl0 = row0 & 2047;
#pragma unroll
            for (int h = 0; h < 2; ++h) {
                if (wn == h) {
#pragma unroll
                    for (int mt = 0; mt < 4; ++mt)
#pragma unroll
                        for (int nt = 0; nt < 4; ++nt)
#pragma unroll
                            for (int r = 0; r < 4; ++r)
                                Tb[nt * 16 + l16][wm * 64 + mt * 16 + quad * 4 + r] =
                                    f2bf(acc[mt][nt][r]);
                }
                __syncthreads();
                const int head = ((col0 - CC) >> 6) + h;
#pragma unroll
                for (int l = 0; l < 4; ++l) {
                    const int idx = t + l * 256;
                    const int dv = idx >> 4, seg = idx & 15;
                    *(s16x8*)(vt + (((size_t)b * HH + head) * DD + dv) * TT + tl0 + seg * 8) =
                        *(const s16x8*)&Tb[dv][seg * 8];
                }
                __syncthreads();
            }
        }
    }
}

// ===== Flash attention v4: S^T orientation + double-buffered K/V prefetch ===
// grid (B*H, 16) with qt2 REVERSED (heaviest first). 256 threads = 4 waves;
// wave w owns 32 queries. One barrier per kt; stage(kt+1) is issued right
// after the barrier so it overlaps compute(kt) before the next barrier's
// vmcnt(0) drain.
// q: bf16 [b][t][QLD] (q|latent fused, pre-scaled by 0.125*log2(e));
// k: bf16 [b][t][h*64+d]; vt: bf16 [b][h][dv][t]; y: bf16 [b][t][c].
extern "C" __global__ __launch_bounds__(256)
void mla_attn2(const unsigned short* __restrict__ q,
               const unsigned short* __restrict__ k,
               const unsigned short* __restrict__ vt,
               unsigned short* __restrict__ y) {
    __shared__ unsigned short Ks[2][64][64];  // [buf][key][d], XOR-swizzled segs
    __shared__ unsigned short Vs[2][64][64];  // [buf][dv][key], XOR-swizzled segs
    __shared__ unsigned short Ps[4][32][72];  // per-wave [qloc][key], padded

    const int bh = blockIdx.x;
    const int qt2 = (gridDim.y - 1) - blockIdx.y;  // big blocks first (LPT packing)
    const int b = bh >> 4, h = bh & 15;
    const int t0 = qt2 * 128;
    const int t = threadIdx.x;
    const int w = t >> 6, lane = t & 63, quad = lane >> 4, l16 = lane & 15;
    const int qw0 = t0 + w * 32;                       // wave's first query
    const int lrow = lane >> 3;                        // row within 8-row chunk
    const int swz = ((lane & 7) ^ lrow) * 8;           // swizzled source seg

    const unsigned short* kb0 = k + ((size_t)b * TT) * CC + h * DD;
    const unsigned short* vb0 = vt + ((size_t)(b * HH + h)) * DD * TT;

    // Q fragments straight from global (pre-scaled), hoisted
    s16x8 qf[2][2];
#pragma unroll
    for (int qs = 0; qs < 2; ++qs)
#pragma unroll
        for (int kh = 0; kh < 2; ++kh)
            qf[qs][kh] = *(const s16x8*)(q + ((size_t)b * TT + qw0 + qs * 16 + l16) * QLD +
                                         h * DD + kh * 32 + quad * 8);

    f32x4 o[2][4];
    float lsum[2] = {0.f, 0.f};
#pragma unroll
    for (int qs = 0; qs < 2; ++qs)
#pragma unroll
        for (int nt = 0; nt < 4; ++nt) o[qs][nt] = (f32x4){0.f, 0.f, 0.f, 0.f};

    const int nkt = 2 * qt2 + 2;

    // prologue: stage tile 0 into buffer 0 (wave w covers chunks w*2, w*2+1)
#pragma unroll
    for (int c = 0; c < 2; ++c) {
        const int g = w * 2 + c;
        const int row = g * 8 + lrow;
        GLDS16(kb0 + (size_t)row * CC + swz, &Ks[0][g * 8][0]);
        GLDS16(vb0 + (size_t)row * TT + swz, &Vs[0][g * 8][0]);
    }

    for (int kt = 0; kt < nkt; ++kt) {
        const int s0 = kt * 64;
        const int cur = kt & 1;
        __syncthreads();  // drains stage(kt) [and any prefetch] -> buf[cur] ready

        // prefetch tile kt+1 into the other buffer; overlaps compute below
        if (kt + 1 < nkt) {
            const int s1 = s0 + 64;
            const int nxt = cur ^ 1;
#pragma unroll
            for (int c = 0; c < 2; ++c) {
                const int g = w * 2 + c;
                const int row = g * 8 + lrow;
                GLDS16(kb0 + (size_t)(s1 + row) * CC + swz, &Ks[nxt][g * 8][0]);
                GLDS16(vb0 + (size_t)row * TT + s1 + swz, &Vs[nxt][g * 8][0]);
            }
        }

        if (s0 <= qw0 + 31) {  // wave-uniform: any unmasked element for this wave?
            // S^T = K Q^T : A=K[m=key], B=Q^T[k=d][n=q]; D row=key, col=q
            f32x4 st[2][4];
#pragma unroll
            for (int nt = 0; nt < 4; ++nt) {
                const int key = nt * 16 + l16;
                const s16x8 kf0 = *(const s16x8*)&Ks[cur][key][((0 + quad) ^ (l16 & 7)) * 8];
                const s16x8 kf1 = *(const s16x8*)&Ks[cur][key][((4 + quad) ^ (l16 & 7)) * 8];
#pragma unroll
                for (int qs = 0; qs < 2; ++qs) {
                    f32x4 acc = (f32x4){0.f, 0.f, 0.f, 0.f};
                    acc = __builtin_amdgcn_mfma_f32_16x16x32_bf16(kf0, qf[qs][0], acc, 0, 0, 0);
                    acc = __builtin_amdgcn_mfma_f32_16x16x32_bf16(kf1, qf[qs][1], acc, 0, 0, 0);
                    st[qs][nt] = acc;
                }
            }

            const bool maskedTile = (s0 + 63 > qw0);  // wave-uniform
#pragma unroll
            for (int qs = 0; qs < 2; ++qs) {
                const int qidx = qw0 + qs * 16 + l16;
#pragma unroll
                for (int nt = 0; nt < 4; ++nt) {
                    const int key0 = s0 + nt * 16 + quad * 4;
                    float p[4];
#pragma unroll
                    for (int r = 0; r < 4; ++r) {
                        float sv = st[qs][nt][r];
                        if (maskedTile && (key0 + r > qidx)) sv = -1e30f;
                        const float e = fast_exp2(sv);
                        p[r] = e;
                        lsum[qs] += e;
                    }
                    const unsigned lo = pack_bf16_trunc(p[0], p[1]);
                    const unsigned hi = pack_bf16_trunc(p[2], p[3]);
                    uint2 pk; pk.x = lo; pk.y = hi;
                    *(uint2*)&Ps[w][qs * 16 + l16][nt * 16 + quad * 4] = pk;
                }
            }

            // PV: A=P[m=q][k=key] from Ps rows; B=V[k=key][n=dv] from Vs rows
            s16x8 pf[2][2];
#pragma unroll
            for (int qs = 0; qs < 2; ++qs)
#pragma unroll
                for (int kh = 0; kh < 2; ++kh)
                    pf[qs][kh] = *(const s16x8*)&Ps[w][qs * 16 + l16][kh * 32 + quad * 8];
#pragma unroll
            for (int nt = 0; nt < 4; ++nt) {
                const int dv = nt * 16 + l16;
                const s16x8 vf0 = *(const s16x8*)&Vs[cur][dv][((0 + quad) ^ (l16 & 7)) * 8];
                const s16x8 vf1 = *(const s16x8*)&Vs[cur][dv][((4 + quad) ^ (l16 & 7)) * 8];
#pragma unroll
                for (int qs = 0; qs < 2; ++qs) {
                    o[qs][nt] = __builtin_amdgcn_mfma_f32_16x16x32_bf16(pf[qs][0], vf0,
                                                                        o[qs][nt], 0, 0, 0);
                    o[qs][nt] = __builtin_amdgcn_mfma_f32_16x16x32_bf16(pf[qs][1], vf1,
                                                                        o[qs][nt], 0, 0, 0);
                }
            }
        }
    }

    // final l reduction: quads hold partial sums for query qs*16+l16
    float lfull[2];
#pragma unroll
    for (int qs = 0; qs < 2; ++qs) {
        float s = lsum[qs];
        s += __shfl_xor(s, 16);
        s += __shfl_xor(s, 32);
        lfull[qs] = s;
    }

    // store: o element = (query qs*16+quad*4+r, dv nt*16+l16)
#pragma unroll
    for (int qs = 0; qs < 2; ++qs) {
#pragma unroll
        for (int r = 0; r < 4; ++r) {
            const float inv = 1.f / __shfl(lfull[qs], quad * 4 + r);
            unsigned short* yb = y + ((size_t)b * TT + qw0 + qs * 16 + quad * 4 + r) * CC +
                                 h * DD + l16;
#pragma unroll
            for (int nt = 0; nt < 4; ++nt)
                yb[nt * 16] = f2bf(o[qs][nt][r] * inv);
        }
    }
}

extern "C" void kernel_launch(void* const* d_in, const int* in_sizes, int n_in,
                              void* d_out, int out_size, void* d_ws, size_t ws_size,
                              hipStream_t stream) {
    const float* x   = (const float*)d_in[0];
    const float* Wq  = (const float*)d_in[1];
    const float* Wkv = (const float*)d_in[2];
    const float* Wk  = (const float*)d_in[3];
    const float* Wv  = (const float*)d_in[4];
    const float* Wo  = (const float*)d_in[5];
    float* out = (float*)d_out;

    const int M = BB * TT;  // 8192
    unsigned short* p = (unsigned short*)d_ws;
    unsigned short* xb    = p; p += (size_t)M * CC;     // bf16 x
    unsigned short* qlatb = p; p += (size_t)M * QLD;    // fused q | latent
    unsigned short* kb    = p; p += (size_t)M * CC;
    unsigned short* vtb   = p; p += (size_t)M * CC;
    unsigned short* yb    = p; p += (size_t)M * CC;
    unsigned short* W1t   = p; p += (size_t)QLD * CC;   // [Wq^T ; Wkv^T]  [1280][1024]
    unsigned short* W2t   = p; p += (size_t)(2 * CC) * LL;  // [Wk^T ; Wv^T] [2048][256]
    unsigned short* Wot   = p; p += (size_t)CC * CC;

    const float qscale = 0.125f * 1.44269504f;  // 1/sqrt(64) * log2(e), folded into Wq

    fused_cvt<<<8896, 256, 0, stream>>>(x, xb, Wq, Wkv, Wk, Wv, Wo,
                                        W1t, W2t, Wot, qscale);
    // fused q|latent projection: [M,1280] = x @ [Wq | Wkv]
    bgemm<1><<<dim3(QLD / 128, M / 128), 256, 0, stream>>>(
        xb, W1t, qlatb, nullptr, M, QLD, CC, CC, QLD);
    // fused k|v up-projection: k half -> kb, v half -> vtb (transposed)
    bgemm<3><<<dim3(2 * CC / 128, M / 128), 256, 0, stream>>>(
        qlatb + CC, W2t, kb, vtb, M, 2 * CC, LL, QLD, CC);
    mla_attn2<<<dim3(BB * HH, TT / 128), 256, 0, stream>>>(qlatb, kb, vtb, yb);
    bgemm<0><<<dim3(CC / 128, M / 128), 256, 0, stream>>>(
        yb, Wot, out, nullptr, M, CC, CC, CC, CC);
}